// Round 9
// baseline (180.861 us; speedup 1.0000x reference)
//
#include <hip/hip_runtime.h>
#include <hip/hip_bf16.h>
#include <math.h>

// Problem constants
#define BB   2
#define CC   256
#define NT   2304      // H*W
#define NTOK 4608      // B*NT
#define MM   16
#define NHD  4
#define HD   64
#define NBH  8
#define LOG2E 1.4426950408889634f

typedef unsigned short u16;
typedef __attribute__((ext_vector_type(8))) short short8;
typedef __attribute__((ext_vector_type(4))) float f32x4;
typedef __attribute__((ext_vector_type(16))) float f32x16;

#if __has_builtin(__builtin_amdgcn_exp2f)
#define EXP2F(x) __builtin_amdgcn_exp2f(x)
#else
#define EXP2F(x) exp2f(x)
#endif

__device__ __forceinline__ float bf2f(u16 u) {
  return __uint_as_float(((unsigned)u) << 16);
}
__device__ __forceinline__ u16 f2bf(float f) {
  unsigned u = __float_as_uint(f);
  unsigned r = 0x7FFFu + ((u >> 16) & 1u);
  return (u16)((u + r) >> 16);
}
__device__ __forceinline__ float ld_any(const void* p, size_t i, int fp32) {
  return fp32 ? ((const float*)p)[i] : bf2f(((const u16*)p)[i]);
}

// per-block dtype detect (bf16 pairs read as u32: low 16 bits look like bf16).
// Contains a barrier: must be called uniformly by the whole block before any
// divergent return.
__device__ __forceinline__ int detect_fp32_block(const unsigned* __restrict__ x) {
  __shared__ int cnt4[4];
  __shared__ int resf;
  int t = threadIdx.x;
  unsigned u = x[t & 255];
  unsigned lo = u & 0xFFFFu;
  unsigned e = (lo >> 7) & 0xFFu;
  bool plausible = (lo == 0u) || (e >= 0x60u && e <= 0x88u);
  unsigned long long m = __ballot(plausible);
  if ((t & 63) == 0 && (t >> 6) < 4) cnt4[t >> 6] = __popcll(m);
  __syncthreads();
  if (t == 0) resf = ((cnt4[0] + cnt4[1] + cnt4[2] + cnt4[3]) < 128) ? 1 : 0;
  __syncthreads();
  return resf;
}

// ---------------- workspace layout (float offsets) ----------------
static constexpr size_t OFF_PHIF  = 16;                   // f32 [4608][16]
static constexpr size_t OFF_PHISQ = OFF_PHIF + 73728;     // f32 [4608]
static constexpr size_t OFF_XFB   = OFF_PHISQ + 4608;     // bf16 [32][4608][8]
static constexpr size_t OFF_QAUG  = OFF_XFB + 589824;     // bf16 [8][16][2304][8]
static constexpr size_t OFF_KAUG  = OFF_QAUG + 1179648;
static constexpr size_t OFF_V3    = OFF_KAUG + 1179648;   // bf16 [8][288][64][8] (row-permuted)
static constexpr size_t OFF_AFRAG = OFF_V3 + 589824;      // bf16 [32][4608][8]
// end ~ 4.21M floats ~ 16.9 MiB

// ================= K1: MLP + xf GEMM, channel-split (72 x 4) ===============
// Stages its W2 slice raw->LDS fragments itself (setup kernel removed).
__global__ __launch_bounds__(256) void prep_xf(
    const void* __restrict__ x_raw, const void* __restrict__ phi_raw,
    const void* __restrict__ W1_r, const void* __restrict__ b1_r,
    const void* __restrict__ W2_r, const void* __restrict__ b2_r,
    float* __restrict__ phif, float* __restrict__ phisq,
    short* __restrict__ xfb) {
  __shared__ float phis[16][66];
  __shared__ float phisq_s[64];
  __shared__ float w1s[2048];
  __shared__ float b1s[128];
  __shared__ short hid[16][66][8];   // A-frags K=128: [kc][tok][8]
  __shared__ short w2s[16][64][8];   // B-frags (this cg's 64 ch): [kc][n][8]

  const int fp32 = detect_fp32_block((const unsigned*)x_raw);
  const int t = threadIdx.x;
  const int n0 = blockIdx.x * 64, cg = blockIdx.y;
  const int b = (n0 >= NT) ? 1 : 0;
  const int nb0 = n0 - b * NT;

  #pragma unroll
  for (int i = 0; i < 4; ++i) {
    int idx = i * 256 + t;
    int m = idx >> 6, j = idx & 63;
    phis[m][j] = ld_any(phi_raw, ((size_t)(b * 16 + m)) * NT + nb0 + j, fp32);
  }
  #pragma unroll
  for (int i = 0; i < 8; ++i) w1s[i * 256 + t] = ld_any(W1_r, i * 256 + t, fp32);
  if (t < 128) b1s[t] = ld_any(b1_r, t, fp32);
  // stage W2 slice [cg*64 .. +64) x 128 -> fragment layout
  #pragma unroll
  for (int i = 0; i < 32; ++i) {
    int idx = i * 256 + t;
    int cl = idx >> 7, k = idx & 127;
    float v = ld_any(W2_r, (size_t)(cg * 64 + cl) * 128 + k, fp32);
    w2s[k >> 3][cl][k & 7] = (short)f2bf(v);
  }
  __syncthreads();

  if (t < 64) {
    float s = 0.f;
    #pragma unroll
    for (int m = 0; m < 16; ++m) { float p = phis[m][t]; s += p * p; }
    phisq_s[t] = s;
    if (cg == 0) phisq[n0 + t] = s;
  }
  if (cg == 0) {
    #pragma unroll
    for (int i = 0; i < 4; ++i) {
      int idx = i * 256 + t;
      int j = idx >> 4, m = idx & 15;
      phif[(size_t)(n0 + j) * 16 + m] = phis[m][j];
    }
  }
  {
    const int tok = t & 63, qtr = t >> 6;
    float pr[16];
    #pragma unroll
    for (int m = 0; m < 16; ++m) pr[m] = phis[m][tok];
    #pragma unroll
    for (int cc = 0; cc < 4; ++cc) {
      union { u16 a[8]; short8 v; } pk;
      #pragma unroll
      for (int s8 = 0; s8 < 8; ++s8) {
        int c = qtr * 32 + cc * 8 + s8;
        float acc = b1s[c];
        #pragma unroll
        for (int m = 0; m < 16; ++m) acc += pr[m] * w1s[c * 16 + m];
        float g = 0.5f * acc * (1.f + erff(acc * 0.70710678118654752f));
        pk.a[s8] = f2bf(g);
      }
      *(short8*)&hid[qtr * 4 + cc][tok][0] = pk.v;
    }
  }
  __syncthreads();

  // xf = hid @ W2^T + b2 + x^T for this block's 64 channels
  const int lane = t & 63, w = t >> 6;
  const int c32 = lane & 31, H = lane >> 5;
  const int tt = w & 1, chh = w >> 1;
  const int ch0 = cg * 64 + chh * 32;
  f32x16 acc;
  #pragma unroll
  for (int r = 0; r < 16; ++r) acc[r] = 0.f;
  #pragma unroll
  for (int s = 0; s < 8; ++s) {
    short8 a = *(const short8*)&hid[2 * s + H][tt * 32 + c32][0];
    short8 bb = *(const short8*)&w2s[2 * s + H][chh * 32 + c32][0];
    acc = __builtin_amdgcn_mfma_f32_32x32x16_bf16(a, bb, acc, 0, 0, 0);
  }
  const int ch = ch0 + c32;
  const float bias = ld_any(b2_r, ch, fp32);
  #pragma unroll
  for (int g = 0; g < 4; ++g) {
    int tok0 = tt * 32 + 8 * g + 4 * H;
    size_t xoff = ((size_t)(b * CC + ch)) * NT + nb0 + tok0;
    float4 xv;
    if (fp32) {
      xv = *(const float4*)&((const float*)x_raw)[xoff];
    } else {
      ushort4 xu = *(const ushort4*)&((const u16*)x_raw)[xoff];
      xv = make_float4(bf2f(xu.x), bf2f(xu.y), bf2f(xu.z), bf2f(xu.w));
    }
    float vals[4] = {xv.x, xv.y, xv.z, xv.w};
    #pragma unroll
    for (int e = 0; e < 4; ++e) {
      float v = acc[4 * g + e] + bias + vals[e];
      int gtok = n0 + tok0 + e;
      xfb[((size_t)(ch >> 3) * NTOK + gtok) * 8 + (ch & 7)] = (short)f2bf(v);
    }
  }
}

// ================= K2: QKV projection (MFMA) + fused aug ===================
// z<3 stage their head's weight slice raw->LDS fragments. aug writes only
// the chunks attn reads: Q 8,9 (qh), 10,11 (ql); K 8,9 (kh), 12,13 (kl), 14.
__global__ __launch_bounds__(256) void qkv_aug(
    const short* __restrict__ xfb,
    const void* __restrict__ x_raw,
    const void* __restrict__ Wq_r, const void* __restrict__ Wk_r,
    const void* __restrict__ Wv_r,
    const void* __restrict__ bq_r, const void* __restrict__ bk_r,
    const void* __restrict__ bv_r,
    const float* __restrict__ phif, const float* __restrict__ phisq,
    const void* __restrict__ la_r, const void* __restrict__ beta_r,
    short* __restrict__ Qaug, short* __restrict__ Kaug, short* __restrict__ V3) {
  __shared__ short wfs[32][64][8];   // 32 KB B-frags for this head's 64 cols
  const int fp32 = detect_fp32_block((const unsigned*)x_raw);
  const int z = blockIdx.z;
  if (z == 3) {
    if (blockIdx.y != 0) return;
    int idx = blockIdx.x * 256 + threadIdx.x;   // < 8*2304 exactly
    int bh = idx / NT, n = idx - bh * NT;
    int b = bh >> 2, h = bh & 3;
    float la = ld_any(la_r, 0, fp32);
    float bet = ld_any(beta_r, h, fp32);
    float coef = -__expf(la) * bet * 0.17677669529663687f * LOG2E;
    float s2c = -2.f * coef;
    u16 sflip = (s2c < 0.f) ? 0x8000u : 0u;
    float s = sqrtf(fabsf(s2c));
    u16 qh[16], ql[16];
    #pragma unroll
    for (int m = 0; m < MM; ++m) {
      float v = s * phif[(size_t)(b * NT + n) * MM + m];
      u16 hv = f2bf(v);
      qh[m] = hv;
      ql[m] = f2bf(v - bf2f(hv));
    }
    float cp = coef * phisq[b * NT + n];
    u16 chi = f2bf(cp);
    u16 clo = f2bf(cp - bf2f(chi));
    union { u16 a[8]; short8 v; } ch;
    auto wr = [&](short* dst, int kq) {
      *(short8*)&dst[((size_t)(bh * 16 + kq) * NT + n) * 8] = ch.v;
    };
    #pragma unroll
    for (int p = 0; p < 8; ++p) ch.a[p] = qh[p];      wr(Qaug, 8);
    #pragma unroll
    for (int p = 0; p < 8; ++p) ch.a[p] = qh[8 + p];  wr(Qaug, 9);
    #pragma unroll
    for (int p = 0; p < 8; ++p) ch.a[p] = ql[p];      wr(Qaug, 10);
    #pragma unroll
    for (int p = 0; p < 8; ++p) ch.a[p] = ql[8 + p];  wr(Qaug, 11);
    #pragma unroll
    for (int p = 0; p < 8; ++p) ch.a[p] = qh[p] ? (u16)(qh[p] ^ sflip) : (u16)0;      wr(Kaug, 8);
    #pragma unroll
    for (int p = 0; p < 8; ++p) ch.a[p] = qh[8+p] ? (u16)(qh[8+p] ^ sflip) : (u16)0;  wr(Kaug, 9);
    #pragma unroll
    for (int p = 0; p < 8; ++p) ch.a[p] = ql[p] ? (u16)(ql[p] ^ sflip) : (u16)0;      wr(Kaug, 12);
    #pragma unroll
    for (int p = 0; p < 8; ++p) ch.a[p] = ql[8+p] ? (u16)(ql[8+p] ^ sflip) : (u16)0;  wr(Kaug, 13);
    #pragma unroll
    for (int p = 0; p < 8; ++p) ch.a[p] = 0;
    ch.a[0] = chi; ch.a[1] = clo;                     wr(Kaug, 14);
    return;
  }

  const void* wraw = (z == 0) ? Wq_r : (z == 1) ? Wk_r : Wv_r;
  const void* braw = (z == 0) ? bq_r : (z == 1) ? bk_r : bv_r;
  const int t = threadIdx.x, lane = t & 63, w = t >> 6;
  const int col = lane & 15, quad = lane >> 4;
  const int t0 = blockIdx.x * 64, head = blockIdx.y, c0 = head * 64;
  const int b = (t0 >= NT) ? 1 : 0;
  const int arow = t0 + w * 16 + col;

  // stage this head's 64 weight rows (x 256 k) raw -> fragment layout
  #pragma unroll
  for (int i = 0; i < 64; ++i) {
    int idx = i * 256 + t;
    int nl = idx >> 8, k = idx & 255;
    float v = ld_any(wraw, (size_t)(c0 + nl) * 256 + k, fp32);
    wfs[k >> 3][nl][k & 7] = (short)f2bf(v);
  }
  __syncthreads();

  f32x4 acc[4];
  #pragma unroll
  for (int ct = 0; ct < 4; ++ct) acc[ct] = (f32x4){0.f, 0.f, 0.f, 0.f};
  #pragma unroll
  for (int c = 0; c < 8; ++c) {
    short8 af = *(const short8*)&xfb[((size_t)(c * 4 + quad) * NTOK + arow) * 8];
    #pragma unroll
    for (int ct = 0; ct < 4; ++ct) {
      short8 bfr = *(const short8*)&wfs[c * 4 + quad][ct * 16 + col][0];
      acc[ct] = __builtin_amdgcn_mfma_f32_16x16x32_bf16(af, bfr, acc[ct], 0, 0, 0);
    }
  }
  const int r0 = t0 + w * 16 + quad * 4;
  const int n0l = r0 - b * NT;
  const int bh = b * NHD + head;
  if (z < 2) {
    short* dst = (z == 0) ? Qaug : Kaug;
    const float sc = (z == 0) ? 0.125f * LOG2E : 1.f;   // softmax scale + log2e in Q
    #pragma unroll
    for (int ct = 0; ct < 4; ++ct) {
      int chh = ct * 16 + col;
      float bb = ld_any(braw, c0 + chh, fp32);
      int kq = chh >> 3, sub = chh & 7;
      #pragma unroll
      for (int reg = 0; reg < 4; ++reg) {
        float v = (acc[ct][reg] + bb) * sc;
        dst[((size_t)(bh * 16 + kq) * NT + n0l + reg) * 8 + sub] = (short)f2bf(v);
      }
    }
  } else {
    #pragma unroll
    for (int ct = 0; ct < 4; ++ct) {
      int d = ct * 16 + col;
      float bb = ld_any(braw, c0 + d, fp32);
      #pragma unroll
      for (int reg = 0; reg < 4; ++reg) {
        int n = n0l + reg;
        // row-permuted V3 so P's natural Sᵀ register order is the A-operand order
        int chunk = (n >> 6) * 8 + ((n >> 5) & 1) * 4 + ((n >> 4) & 1) * 2 + ((n >> 2) & 1);
        int jj = (n & 3) + 4 * ((n >> 3) & 1);
        V3[((size_t)(bh * 288 + chunk) * 64 + d) * 8 + jj] = (short)f2bf(acc[ct][reg] + bb);
      }
    }
  }
}

// ================= K3: attention v7 =======================================
// Same structure as v6 (576 XCD-pinned blocks, 4 kh-waves, register-deduped
// aug chunks, launch_bounds(256,3)) with the VALU diet:
//   - raw v_exp_f32 (EXP2F) instead of libm exp2f
//   - int voffset induction vars (uniform SGPR base + one v_add per load)
__global__ __launch_bounds__(256, 3) void attn_v7(
    const short* __restrict__ Qaug, const short* __restrict__ Kaug,
    const short* __restrict__ V3, short* __restrict__ afrag) {
  __shared__ float obuf[3][2][16][64];   // 24 KB
  __shared__ float lbuf[3][32];
  __shared__ float lfin[32];

  const int t = threadIdx.x, lane = t & 63, kh = t >> 6;
  const int c32 = lane & 31, H = lane >> 5;
  const int bid = blockIdx.x;
  const int bh = bid & 7, qt = bid >> 3;
  const int q0 = qt * 32;
  const int bg = bh >> 2, hh = bh & 3;

  // block-uniform bases (SGPR) + int lane offsets (VGPR)
  const short* qbase = Qaug + bh * (16 * NT * 8);
  const short* kbase = Kaug + bh * (16 * NT * 8);
  const short* vbase = V3 + bh * (288 * 64 * 8);
  const int NT8 = NT * 8;              // 18432
  const int CH2 = 2 * NT8;             // chunk-pair stride 36864

  short8 qf[6];
  #pragma unroll
  for (int s = 0; s < 6; ++s)
    qf[s] = *(const short8*)&qbase[(2 * s + H) * NT8 + (q0 + c32) * 8];
  short8 qf7;
  {
    union { u16 a[8]; short8 v; } c7;
    #pragma unroll
    for (int p = 0; p < 8; ++p) c7.a[p] = 0;
    if (H == 0) { c7.a[0] = 0x3F80u; c7.a[1] = 0x3F80u; }
    qf7 = c7.v;
  }

  f32x16 o[2];
  #pragma unroll
  for (int nt = 0; nt < 2; ++nt)
    #pragma unroll
    for (int r = 0; r < 16; ++r) o[nt][r] = 0.f;
  float lsum = 0.f;

  int vk  = H * NT8 + (kh * 32 + c32) * 8;     // K rows, chunks 0.. (+H)
  int vk7 = 14 * NT8 + (kh * 32 + c32) * 8;    // K chunk 14 (both halves)
  int vv  = ((kh >> 1) * 8 + (kh & 1) * 4 + H) * 512 + c32 * 8;

  short8 kf[5], kf6, kf7, vf[4];
  #pragma unroll
  for (int s = 0; s < 5; ++s)
    kf[s] = *(const short8*)&kbase[vk + s * CH2];
  kf6 = *(const short8*)&kbase[vk + 12 * NT8];
  kf7 = *(const short8*)&kbase[vk7];
  #pragma unroll
  for (int st = 0; st < 2; ++st)
    #pragma unroll
    for (int nt = 0; nt < 2; ++nt)
      vf[st * 2 + nt] = *(const short8*)&vbase[vv + st * 1024 + nt * 256];

  auto iter = [&](bool pref) {
    const int nk = vk + 1024, nk7 = vk7 + 1024, nv = vv + 8192;
    f32x16 sa;
    #pragma unroll
    for (int r = 0; r < 16; ++r) sa[r] = 0.f;
    #pragma unroll
    for (int s = 0; s < 4; ++s) {
      sa = __builtin_amdgcn_mfma_f32_32x32x16_bf16(kf[s], qf[s], sa, 0, 0, 0);
      if (pref) kf[s] = *(const short8*)&kbase[nk + s * CH2];
    }
    sa = __builtin_amdgcn_mfma_f32_32x32x16_bf16(kf[4], qf[4], sa, 0, 0, 0);  // kh*qh
    sa = __builtin_amdgcn_mfma_f32_32x32x16_bf16(kf[4], qf[5], sa, 0, 0, 0);  // kh*ql
    if (pref) kf[4] = *(const short8*)&kbase[nk + 4 * CH2];
    sa = __builtin_amdgcn_mfma_f32_32x32x16_bf16(kf6, qf[4], sa, 0, 0, 0);    // kl*qh
    if (pref) kf6 = *(const short8*)&kbase[nk + 12 * NT8];
    sa = __builtin_amdgcn_mfma_f32_32x32x16_bf16(kf7, qf7, sa, 0, 0, 0);      // psq_j
    if (pref) kf7 = *(const short8*)&kbase[nk7];

    float p[16];
    #pragma unroll
    for (int r = 0; r < 16; ++r) { p[r] = EXP2F(sa[r]); lsum += p[r]; }

    short8 pf[2];
    #pragma unroll
    for (int st = 0; st < 2; ++st) {
      union { unsigned u[4]; short8 v; } pk;
      #pragma unroll
      for (int j2 = 0; j2 < 4; ++j2) {
        __hip_bfloat162 hh2 = __float22bfloat162_rn(
            make_float2(p[8 * st + 2 * j2], p[8 * st + 2 * j2 + 1]));
        pk.u[j2] = *(unsigned*)&hh2;
      }
      pf[st] = pk.v;
    }

    #pragma unroll
    for (int st = 0; st < 2; ++st)
      #pragma unroll
      for (int nt = 0; nt < 2; ++nt) {
        o[nt] = __builtin_amdgcn_mfma_f32_32x32x16_bf16(pf[st], vf[st * 2 + nt],
                                                        o[nt], 0, 0, 0);
        if (pref)
          vf[st * 2 + nt] = *(const short8*)&vbase[nv + st * 1024 + nt * 256];
      }
    vk = nk; vk7 = nk7; vv = nv;
  };

  #pragma unroll 1
  for (int it = 0; it < 17; ++it) iter(true);
  iter(false);

  lsum += __shfl_xor(lsum, 32, 64);

  // ---- 4-way kh merge: kh1..3 dump, one barrier, kh0 finishes
  if (kh != 0) {
    #pragma unroll
    for (int nt = 0; nt < 2; ++nt)
      #pragma unroll
      for (int r = 0; r < 16; ++r) obuf[kh - 1][nt][r][lane] = o[nt][r];
    if (H == 0) lbuf[kh - 1][c32] = lsum;
  }
  __syncthreads();
  if (kh == 0) {
    #pragma unroll
    for (int sl = 0; sl < 3; ++sl) {
      #pragma unroll
      for (int nt = 0; nt < 2; ++nt)
        #pragma unroll
        for (int r = 0; r < 16; ++r) o[nt][r] += obuf[sl][nt][r][lane];
      lsum += lbuf[sl][c32];
    }
    if (H == 0) lfin[c32] = lsum;   // same-wave LDS round-trip (no barrier)
    float4 linv[4];
    #pragma unroll
    for (int g = 0; g < 4; ++g) {
      float4 lv = *(const float4*)&lfin[8 * g + 4 * H];
      linv[g] = make_float4(1.f / lv.x, 1.f / lv.y, 1.f / lv.z, 1.f / lv.w);
    }
    #pragma unroll
    for (int nt = 0; nt < 2; ++nt) {
      int c = hh * 64 + nt * 32 + c32;
      size_t cbase = (size_t)(c >> 3) * NTOK * 8 + (c & 7);
      #pragma unroll
      for (int r = 0; r < 16; ++r) {
        float inv = (r & 3) == 0 ? linv[r >> 2].x : (r & 3) == 1 ? linv[r >> 2].y
                  : (r & 3) == 2 ? linv[r >> 2].z : linv[r >> 2].w;
        int n = q0 + (r & 3) + 8 * (r >> 2) + 4 * H;
        afrag[cbase + (size_t)(bg * NT + n) * 8] = (short)f2bf(o[nt][r] * inv);
      }
    }
  }
}

// ================= K4: out projection, channel-split (72 x 4) ==============
__global__ __launch_bounds__(256) void oproj4(
    const short* __restrict__ afrag, const void* __restrict__ Wo_r,
    const void* __restrict__ bo_r, void* __restrict__ outp,
    const void* __restrict__ x_raw) {
  __shared__ short wos[32][64][8];   // 32 KB B-frags for this cg's 64 rows
  const int fp32 = detect_fp32_block((const unsigned*)x_raw);
  const int t = threadIdx.x, lane = t & 63, w = t >> 6;
  const int c32 = lane & 31, H = lane >> 5;
  const int t0 = blockIdx.x * 64, cg = blockIdx.y;
  const int b = (t0 >= NT) ? 1 : 0;
  const int nb0 = t0 - b * NT;
  const int tt = w & 1, chh = w >> 1;
  const int ch0 = cg * 64 + chh * 32;

  #pragma unroll
  for (int i = 0; i < 64; ++i) {
    int idx = i * 256 + t;
    int nl = idx >> 8, k = idx & 255;
    float v = ld_any(Wo_r, (size_t)(cg * 64 + nl) * 256 + k, fp32);
    wos[k >> 3][nl][k & 7] = (short)f2bf(v);
  }
  __syncthreads();

  f32x16 acc;
  #pragma unroll
  for (int r = 0; r < 16; ++r) acc[r] = 0.f;
  #pragma unroll
  for (int s = 0; s < 16; ++s) {
    short8 a = *(const short8*)&wos[2 * s + H][chh * 32 + c32][0];
    short8 bb = *(const short8*)&afrag[((size_t)(2 * s + H) * NTOK + t0 + tt * 32 + c32) * 8];
    acc = __builtin_amdgcn_mfma_f32_32x32x16_bf16(a, bb, acc, 0, 0, 0);
  }
  #pragma unroll
  for (int r = 0; r < 16; ++r) {
    int co = ch0 + (r & 3) + 8 * (r >> 2) + 4 * H;
    float v = acc[r] + ld_any(bo_r, co, fp32);
    size_t off = ((size_t)(b * CC + co)) * NT + nb0 + tt * 32 + c32;
    if (fp32) ((float*)outp)[off] = v;
    else      ((u16*)outp)[off] = f2bf(v);
  }
}

extern "C" void kernel_launch(void* const* d_in, const int* in_sizes, int n_in,
                              void* d_out, int out_size, void* d_ws, size_t ws_size,
                              hipStream_t stream) {
  float* ws = (float*)d_ws;
  short* ws16 = (short*)d_ws;

  float* phif = ws + OFF_PHIF; float* phisq = ws + OFF_PHISQ;
  short* xfb   = ws16 + OFF_XFB * 2;
  short* qaug  = ws16 + OFF_QAUG * 2;
  short* kaug  = ws16 + OFF_KAUG * 2;
  short* v3    = ws16 + OFF_V3 * 2;
  short* afrag = ws16 + OFF_AFRAG * 2;

  prep_xf<<<dim3(72, 4), 256, 0, stream>>>(
      d_in[0], d_in[1], d_in[11], d_in[12], d_in[13], d_in[14],
      phif, phisq, xfb);
  qkv_aug<<<dim3(72, 4, 4), 256, 0, stream>>>(
      xfb, d_in[0], d_in[3], d_in[5], d_in[7], d_in[4], d_in[6], d_in[8],
      phif, phisq, d_in[15], d_in[16], qaug, kaug, v3);
  attn_v7<<<576, 256, 0, stream>>>(qaug, kaug, v3, afrag);
  oproj4<<<dim3(72, 4), 256, 0, stream>>>(afrag, d_in[9], d_in[10], d_out, d_in[0]);
}

// Round 10
// 145.156 us; speedup vs baseline: 1.2460x; 1.2460x over previous
//
#include <hip/hip_runtime.h>
#include <hip/hip_bf16.h>
#include <math.h>

// Problem constants
#define BB   2
#define CC   256
#define NT   2304      // H*W
#define NTOK 4608      // B*NT
#define MM   16
#define NHD  4
#define HD   64
#define NBH  8
#define LOG2E 1.4426950408889634f

typedef unsigned short u16;
typedef __attribute__((ext_vector_type(8))) short short8;
typedef __attribute__((ext_vector_type(4))) float f32x4;
typedef __attribute__((ext_vector_type(16))) float f32x16;

#if __has_builtin(__builtin_amdgcn_exp2f)
#define EXP2F(x) __builtin_amdgcn_exp2f(x)
#else
#define EXP2F(x) exp2f(x)
#endif

__device__ __forceinline__ float bf2f(u16 u) {
  return __uint_as_float(((unsigned)u) << 16);
}
__device__ __forceinline__ u16 f2bf(float f) {
  unsigned u = __float_as_uint(f);
  unsigned r = 0x7FFFu + ((u >> 16) & 1u);
  return (u16)((u + r) >> 16);
}
__device__ __forceinline__ float ld_any(const void* p, size_t i, int fp32) {
  return fp32 ? ((const float*)p)[i] : bf2f(((const u16*)p)[i]);
}

// per-block dtype detect (bf16 pairs read as u32: low 16 bits look like bf16)
__device__ __forceinline__ int detect_fp32_block(const unsigned* __restrict__ x) {
  __shared__ int cnt4[4];
  __shared__ int resf;
  int t = threadIdx.x;
  unsigned u = x[t & 255];
  unsigned lo = u & 0xFFFFu;
  unsigned e = (lo >> 7) & 0xFFu;
  bool plausible = (lo == 0u) || (e >= 0x60u && e <= 0x88u);
  unsigned long long m = __ballot(plausible);
  if ((t & 63) == 0 && (t >> 6) < 4) cnt4[t >> 6] = __popcll(m);
  __syncthreads();
  if (t == 0) resf = ((cnt4[0] + cnt4[1] + cnt4[2] + cnt4[3]) < 128) ? 1 : 0;
  __syncthreads();
  return resf;
}

// ---------------- workspace layout (float offsets); flag = int at ws[0] ----
static constexpr size_t OFF_CB2   = 16;
static constexpr size_t OFF_CBQ   = OFF_CB2 + 256;
static constexpr size_t OFF_CBK   = OFF_CBQ + 256;
static constexpr size_t OFF_CBV   = OFF_CBK + 256;
static constexpr size_t OFF_CBO   = OFF_CBV + 256;
static constexpr size_t OFF_CLA   = OFF_CBO + 256;
static constexpr size_t OFF_CBETA = OFF_CLA + 16;
static constexpr size_t OFF_WQF   = 1344;                 // bf16 [32][256][8]
static constexpr size_t OFF_WKF   = OFF_WQF + 32768;
static constexpr size_t OFF_WVF   = OFF_WKF + 32768;
static constexpr size_t OFF_WOF   = OFF_WVF + 32768;
static constexpr size_t OFF_W2F   = OFF_WOF + 32768;      // bf16 [16][256][8]
static constexpr size_t OFF_XFB   = OFF_W2F + 16384;      // bf16 [32][4608][8]
static constexpr size_t OFF_QAUG  = OFF_XFB + 589824;     // bf16 [8][16][2304][8]
static constexpr size_t OFF_KAUG  = OFF_QAUG + 1179648;
static constexpr size_t OFF_V3    = OFF_KAUG + 1179648;   // bf16 [8][288][64][8] (row-permuted)
static constexpr size_t OFF_PHIF  = OFF_V3 + 589824;      // f32 [4608][16]
static constexpr size_t OFF_PHISQ = OFF_PHIF + 73728;     // f32 [4608]
static constexpr size_t OFF_AFRAG = OFF_PHISQ + 4608;     // bf16 [32][4608][8]
// end ~ 4.36M floats ~ 17.4 MiB

// ================= K1: pack weights + convert smalls + flag ================
__global__ __launch_bounds__(256) void setup_kernel(
    const void* __restrict__ x_raw,
    const void* __restrict__ Wq_r, const void* __restrict__ Wk_r,
    const void* __restrict__ Wv_r, const void* __restrict__ Wo_r,
    const void* __restrict__ W2_r,
    const void* __restrict__ b2_r, const void* __restrict__ bq_r,
    const void* __restrict__ bk_r, const void* __restrict__ bv_r,
    const void* __restrict__ bo_r, const void* __restrict__ la_r,
    const void* __restrict__ beta_r,
    float* __restrict__ ws, short* __restrict__ ws16, int* __restrict__ flagp) {
  const int fp32 = detect_fp32_block((const unsigned*)x_raw);
  const int bid = blockIdx.x, t = threadIdx.x;
  if (bid == 0 && t == 0) *flagp = fp32;
  if (bid < 1152) {
    // pack weights to bf16 fragment layout: W[n][k] -> [k>>3][n][k&7]
    int idx = bid * 256 + t;   // < 294912
    const void* srcs[5] = {Wq_r, Wk_r, Wv_r, Wo_r, W2_r};
    const int elems[5] = {65536, 65536, 65536, 65536, 32768};
    const int ksh[5] = {8, 8, 8, 8, 7};
    const size_t dsts[5] = {OFF_WQF * 2, OFF_WKF * 2, OFF_WVF * 2, OFF_WOF * 2, OFF_W2F * 2};
    int m = 0, off = idx;
    while (off >= elems[m]) { off -= elems[m]; ++m; }
    int ks = ksh[m];
    int n = off >> ks, k = off & ((1 << ks) - 1);
    float v = ld_any(srcs[m], off, fp32);
    ws16[dsts[m] + ((size_t)(k >> 3) * 256 + n) * 8 + (k & 7)] = (short)f2bf(v);
  } else {
    int idx = (bid - 1152) * 256 + t;   // < 1285
    const void* srcs[7] = {b2_r, bq_r, bk_r, bv_r, bo_r, la_r, beta_r};
    const int sizes[7] = {256, 256, 256, 256, 256, 1, 4};
    const int dsts[7] = {(int)OFF_CB2, (int)OFF_CBQ, (int)OFF_CBK, (int)OFF_CBV,
                         (int)OFF_CBO, (int)OFF_CLA, (int)OFF_CBETA};
    if (idx < 1285) {
      int seg = 0, off = idx;
      while (off >= sizes[seg]) { off -= sizes[seg]; ++seg; }
      ws[(size_t)dsts[seg] + off] = ld_any(srcs[seg], off, fp32);
    }
  }
}

// ================= K2: MLP + xf GEMM, channel-split (72 tiles x 4 chgroups) =
__global__ __launch_bounds__(256) void prep_xf(
    const void* __restrict__ x_raw, const void* __restrict__ phi_raw,
    const void* __restrict__ W1_r, const void* __restrict__ b1_r,
    const int* __restrict__ flagp,
    const short* __restrict__ w2f, const float* __restrict__ b2,
    float* __restrict__ phif, float* __restrict__ phisq,
    short* __restrict__ xfb) {
  __shared__ float phis[16][66];
  __shared__ float phisq_s[64];
  __shared__ float w1s[2048];
  __shared__ float b1s[128];
  __shared__ short hid[16][66][8];   // A-frags K=128: [kc][tok][8]

  const int fp32 = *flagp;
  const int t = threadIdx.x;
  const int n0 = blockIdx.x * 64, cg = blockIdx.y;
  const int b = (n0 >= NT) ? 1 : 0;
  const int nb0 = n0 - b * NT;

  #pragma unroll
  for (int i = 0; i < 4; ++i) {
    int idx = i * 256 + t;
    int m = idx >> 6, j = idx & 63;
    phis[m][j] = ld_any(phi_raw, ((size_t)(b * 16 + m)) * NT + nb0 + j, fp32);
  }
  #pragma unroll
  for (int i = 0; i < 8; ++i) w1s[i * 256 + t] = ld_any(W1_r, i * 256 + t, fp32);
  if (t < 128) b1s[t] = ld_any(b1_r, t, fp32);
  __syncthreads();

  if (t < 64) {
    float s = 0.f;
    #pragma unroll
    for (int m = 0; m < 16; ++m) { float p = phis[m][t]; s += p * p; }
    phisq_s[t] = s;
    if (cg == 0) phisq[n0 + t] = s;
  }
  if (cg == 0) {
    #pragma unroll
    for (int i = 0; i < 4; ++i) {
      int idx = i * 256 + t;
      int j = idx >> 4, m = idx & 15;
      phif[(size_t)(n0 + j) * 16 + m] = phis[m][j];
    }
  }
  {
    const int tok = t & 63, qtr = t >> 6;
    float pr[16];
    #pragma unroll
    for (int m = 0; m < 16; ++m) pr[m] = phis[m][tok];
    #pragma unroll
    for (int cc = 0; cc < 4; ++cc) {
      union { u16 a[8]; short8 v; } pk;
      #pragma unroll
      for (int s8 = 0; s8 < 8; ++s8) {
        int c = qtr * 32 + cc * 8 + s8;
        float acc = b1s[c];
        #pragma unroll
        for (int m = 0; m < 16; ++m) acc += pr[m] * w1s[c * 16 + m];
        float g = 0.5f * acc * (1.f + erff(acc * 0.70710678118654752f));
        pk.a[s8] = f2bf(g);
      }
      *(short8*)&hid[qtr * 4 + cc][tok][0] = pk.v;
    }
  }
  __syncthreads();

  // xf = hid @ W2^T + b2 + x^T for this block's 64 channels
  const int lane = t & 63, w = t >> 6;
  const int c32 = lane & 31, H = lane >> 5;
  const int tt = w & 1, chh = w >> 1;
  const int ch0 = cg * 64 + chh * 32;
  f32x16 acc;
  #pragma unroll
  for (int r = 0; r < 16; ++r) acc[r] = 0.f;
  #pragma unroll
  for (int s = 0; s < 8; ++s) {
    short8 a = *(const short8*)&hid[2 * s + H][tt * 32 + c32][0];
    short8 bb = *(const short8*)&w2f[((size_t)(2 * s + H) * 256 + ch0 + c32) * 8];
    acc = __builtin_amdgcn_mfma_f32_32x32x16_bf16(a, bb, acc, 0, 0, 0);
  }
  const int ch = ch0 + c32;
  const float bias = b2[ch];
  #pragma unroll
  for (int g = 0; g < 4; ++g) {
    int tok0 = tt * 32 + 8 * g + 4 * H;
    size_t xoff = ((size_t)(b * CC + ch)) * NT + nb0 + tok0;
    float4 xv;
    if (fp32) {
      xv = *(const float4*)&((const float*)x_raw)[xoff];
    } else {
      ushort4 xu = *(const ushort4*)&((const u16*)x_raw)[xoff];
      xv = make_float4(bf2f(xu.x), bf2f(xu.y), bf2f(xu.z), bf2f(xu.w));
    }
    float vals[4] = {xv.x, xv.y, xv.z, xv.w};
    #pragma unroll
    for (int e = 0; e < 4; ++e) {
      float v = acc[4 * g + e] + bias + vals[e];
      int gtok = n0 + tok0 + e;
      xfb[((size_t)(ch >> 3) * NTOK + gtok) * 8 + (ch & 7)] = (short)f2bf(v);
    }
  }
}

// ================= K3: QKV projection (MFMA) + fused aug ===================
// aug writes only the chunks attn reads: Q 8,9 (qh), 10,11 (ql);
// K 8,9 (kh), 12,13 (kl), 14 (chi,clo).
__global__ __launch_bounds__(256) void qkv_aug(
    const short* __restrict__ xfb,
    const short* __restrict__ wqf, const short* __restrict__ wkf,
    const short* __restrict__ wvf,
    const float* __restrict__ bq, const float* __restrict__ bk,
    const float* __restrict__ bv,
    const float* __restrict__ phif, const float* __restrict__ phisq,
    const float* __restrict__ la, const float* __restrict__ beta,
    short* __restrict__ Qaug, short* __restrict__ Kaug, short* __restrict__ V3) {
  const int z = blockIdx.z;
  if (z == 3) {
    if (blockIdx.y != 0) return;
    int idx = blockIdx.x * 256 + threadIdx.x;
    if (idx >= NBH * NT) return;
    int bh = idx / NT, n = idx - bh * NT;
    int b = bh >> 2, h = bh & 3;
    float coef = -__expf(la[0]) * beta[h] * 0.17677669529663687f * LOG2E;
    float s2c = -2.f * coef;
    u16 sflip = (s2c < 0.f) ? 0x8000u : 0u;
    float s = sqrtf(fabsf(s2c));
    u16 qh[16], ql[16];
    #pragma unroll
    for (int m = 0; m < MM; ++m) {
      float v = s * phif[(size_t)(b * NT + n) * MM + m];
      u16 hv = f2bf(v);
      qh[m] = hv;
      ql[m] = f2bf(v - bf2f(hv));
    }
    float cp = coef * phisq[b * NT + n];
    u16 chi = f2bf(cp);
    u16 clo = f2bf(cp - bf2f(chi));
    union { u16 a[8]; short8 v; } ch;
    auto wr = [&](short* dst, int kq) {
      *(short8*)&dst[((size_t)(bh * 16 + kq) * NT + n) * 8] = ch.v;
    };
    #pragma unroll
    for (int p = 0; p < 8; ++p) ch.a[p] = qh[p];      wr(Qaug, 8);
    #pragma unroll
    for (int p = 0; p < 8; ++p) ch.a[p] = qh[8 + p];  wr(Qaug, 9);
    #pragma unroll
    for (int p = 0; p < 8; ++p) ch.a[p] = ql[p];      wr(Qaug, 10);
    #pragma unroll
    for (int p = 0; p < 8; ++p) ch.a[p] = ql[8 + p];  wr(Qaug, 11);
    #pragma unroll
    for (int p = 0; p < 8; ++p) ch.a[p] = qh[p] ? (u16)(qh[p] ^ sflip) : (u16)0;      wr(Kaug, 8);
    #pragma unroll
    for (int p = 0; p < 8; ++p) ch.a[p] = qh[8+p] ? (u16)(qh[8+p] ^ sflip) : (u16)0;  wr(Kaug, 9);
    #pragma unroll
    for (int p = 0; p < 8; ++p) ch.a[p] = ql[p] ? (u16)(ql[p] ^ sflip) : (u16)0;      wr(Kaug, 12);
    #pragma unroll
    for (int p = 0; p < 8; ++p) ch.a[p] = ql[8+p] ? (u16)(ql[8+p] ^ sflip) : (u16)0;  wr(Kaug, 13);
    #pragma unroll
    for (int p = 0; p < 8; ++p) ch.a[p] = 0;
    ch.a[0] = chi; ch.a[1] = clo;                     wr(Kaug, 14);
    return;
  }

  const short* wf = (z == 0) ? wqf : (z == 1) ? wkf : wvf;
  const float* bias = (z == 0) ? bq : (z == 1) ? bk : bv;
  const int t = threadIdx.x, lane = t & 63, w = t >> 6;
  const int col = lane & 15, quad = lane >> 4;
  const int t0 = blockIdx.x * 64, head = blockIdx.y, c0 = head * 64;
  const int b = (t0 >= NT) ? 1 : 0;
  const int arow = t0 + w * 16 + col;
  f32x4 acc[4];
  #pragma unroll
  for (int ct = 0; ct < 4; ++ct) acc[ct] = (f32x4){0.f, 0.f, 0.f, 0.f};
  #pragma unroll
  for (int c = 0; c < 8; ++c) {
    short8 af = *(const short8*)&xfb[((size_t)(c * 4 + quad) * NTOK + arow) * 8];
    #pragma unroll
    for (int ct = 0; ct < 4; ++ct) {
      short8 bfr = *(const short8*)&wf[((size_t)(c * 4 + quad) * 256 + c0 + ct * 16 + col) * 8];
      acc[ct] = __builtin_amdgcn_mfma_f32_16x16x32_bf16(af, bfr, acc[ct], 0, 0, 0);
    }
  }
  const int r0 = t0 + w * 16 + quad * 4;
  const int n0l = r0 - b * NT;
  const int bh = b * NHD + head;
  if (z < 2) {
    short* dst = (z == 0) ? Qaug : Kaug;
    const float sc = (z == 0) ? 0.125f * LOG2E : 1.f;   // softmax scale + log2e in Q
    #pragma unroll
    for (int ct = 0; ct < 4; ++ct) {
      int chh = ct * 16 + col;
      float bb = bias[c0 + chh];
      int kq = chh >> 3, sub = chh & 7;
      #pragma unroll
      for (int reg = 0; reg < 4; ++reg) {
        float v = (acc[ct][reg] + bb) * sc;
        dst[((size_t)(bh * 16 + kq) * NT + n0l + reg) * 8 + sub] = (short)f2bf(v);
      }
    }
  } else {
    #pragma unroll
    for (int ct = 0; ct < 4; ++ct) {
      int d = ct * 16 + col;
      float bb = bias[c0 + d];
      #pragma unroll
      for (int reg = 0; reg < 4; ++reg) {
        int n = n0l + reg;
        // row-permuted V3 so P's natural Sᵀ register order is the A-operand order
        int chunk = (n >> 6) * 8 + ((n >> 5) & 1) * 4 + ((n >> 4) & 1) * 2 + ((n >> 2) & 1);
        int jj = (n & 3) + 4 * ((n >> 3) & 1);
        V3[((size_t)(bh * 288 + chunk) * 64 + d) * 8 + jj] = (short)f2bf(acc[ct][reg] + bb);
      }
    }
  }
}

// ================= K4: attention v8 =======================================
// R8's proven structure (576 XCD-pinned blocks, 4 kh-waves, register-deduped
// aug chunks, launch_bounds(256,3), 4-way LDS kh-merge) + the R9-verified
// VALU diet: raw v_exp_f32 (EXP2F) and 32-bit voffset induction variables.
__global__ __launch_bounds__(256, 3) void attn_v8(
    const short* __restrict__ Qaug, const short* __restrict__ Kaug,
    const short* __restrict__ V3, short* __restrict__ afrag) {
  __shared__ float obuf[3][2][16][64];   // 24 KB
  __shared__ float lbuf[3][32];
  __shared__ float lfin[32];

  const int t = threadIdx.x, lane = t & 63, kh = t >> 6;
  const int c32 = lane & 31, H = lane >> 5;
  const int bid = blockIdx.x;
  const int bh = bid & 7, qt = bid >> 3;
  const int q0 = qt * 32;
  const int bg = bh >> 2, hh = bh & 3;

  // block-uniform bases (SGPR) + 32-bit lane offsets (VGPR induction)
  const short* qbase = Qaug + bh * (16 * NT * 8);
  const short* kbase = Kaug + bh * (16 * NT * 8);
  const short* vbase = V3 + bh * (288 * 64 * 8);
  const int NT8 = NT * 8;              // 18432
  const int CH2 = 2 * NT8;             // chunk-pair stride

  short8 qf[6];
  #pragma unroll
  for (int s = 0; s < 6; ++s)
    qf[s] = *(const short8*)&qbase[(2 * s + H) * NT8 + (q0 + c32) * 8];
  short8 qf7;
  {
    union { u16 a[8]; short8 v; } c7;
    #pragma unroll
    for (int p = 0; p < 8; ++p) c7.a[p] = 0;
    if (H == 0) { c7.a[0] = 0x3F80u; c7.a[1] = 0x3F80u; }
    qf7 = c7.v;
  }

  f32x16 o[2];
  #pragma unroll
  for (int nt = 0; nt < 2; ++nt)
    #pragma unroll
    for (int r = 0; r < 16; ++r) o[nt][r] = 0.f;
  float lsum = 0.f;

  int vk  = H * NT8 + (kh * 32 + c32) * 8;     // K rows, chunks 0.. (+H)
  int vk7 = 14 * NT8 + (kh * 32 + c32) * 8;    // K chunk 14 (both halves)
  int vv  = ((kh >> 1) * 8 + (kh & 1) * 4 + H) * 512 + c32 * 8;

  short8 kf[5], kf6, kf7, vf[4];
  #pragma unroll
  for (int s = 0; s < 5; ++s)
    kf[s] = *(const short8*)&kbase[vk + s * CH2];
  kf6 = *(const short8*)&kbase[vk + 12 * NT8];
  kf7 = *(const short8*)&kbase[vk7];
  #pragma unroll
  for (int st = 0; st < 2; ++st)
    #pragma unroll
    for (int nt = 0; nt < 2; ++nt)
      vf[st * 2 + nt] = *(const short8*)&vbase[vv + st * 1024 + nt * 256];

  auto iter = [&](bool pref) {
    const int nk = vk + 1024, nk7 = vk7 + 1024, nv = vv + 8192;
    f32x16 sa;
    #pragma unroll
    for (int r = 0; r < 16; ++r) sa[r] = 0.f;
    #pragma unroll
    for (int s = 0; s < 4; ++s) {
      sa = __builtin_amdgcn_mfma_f32_32x32x16_bf16(kf[s], qf[s], sa, 0, 0, 0);
      if (pref) kf[s] = *(const short8*)&kbase[nk + s * CH2];
    }
    sa = __builtin_amdgcn_mfma_f32_32x32x16_bf16(kf[4], qf[4], sa, 0, 0, 0);  // kh*qh
    sa = __builtin_amdgcn_mfma_f32_32x32x16_bf16(kf[4], qf[5], sa, 0, 0, 0);  // kh*ql
    if (pref) kf[4] = *(const short8*)&kbase[nk + 4 * CH2];
    sa = __builtin_amdgcn_mfma_f32_32x32x16_bf16(kf6, qf[4], sa, 0, 0, 0);    // kl*qh
    if (pref) kf6 = *(const short8*)&kbase[nk + 12 * NT8];
    sa = __builtin_amdgcn_mfma_f32_32x32x16_bf16(kf7, qf7, sa, 0, 0, 0);      // psq_j
    if (pref) kf7 = *(const short8*)&kbase[nk7];

    float p[16];
    #pragma unroll
    for (int r = 0; r < 16; ++r) { p[r] = EXP2F(sa[r]); lsum += p[r]; }

    short8 pf[2];
    #pragma unroll
    for (int st = 0; st < 2; ++st) {
      union { unsigned u[4]; short8 v; } pk;
      #pragma unroll
      for (int j2 = 0; j2 < 4; ++j2) {
        __hip_bfloat162 hh2 = __float22bfloat162_rn(
            make_float2(p[8 * st + 2 * j2], p[8 * st + 2 * j2 + 1]));
        pk.u[j2] = *(unsigned*)&hh2;
      }
      pf[st] = pk.v;
    }

    #pragma unroll
    for (int st = 0; st < 2; ++st)
      #pragma unroll
      for (int nt = 0; nt < 2; ++nt) {
        o[nt] = __builtin_amdgcn_mfma_f32_32x32x16_bf16(pf[st], vf[st * 2 + nt],
                                                        o[nt], 0, 0, 0);
        if (pref)
          vf[st * 2 + nt] = *(const short8*)&vbase[nv + st * 1024 + nt * 256];
      }
    vk = nk; vk7 = nk7; vv = nv;
  };

  #pragma unroll 1
  for (int it = 0; it < 17; ++it) iter(true);
  iter(false);

  lsum += __shfl_xor(lsum, 32, 64);

  // ---- 4-way kh merge: kh1..3 dump, one barrier, kh0 finishes
  if (kh != 0) {
    #pragma unroll
    for (int nt = 0; nt < 2; ++nt)
      #pragma unroll
      for (int r = 0; r < 16; ++r) obuf[kh - 1][nt][r][lane] = o[nt][r];
    if (H == 0) lbuf[kh - 1][c32] = lsum;
  }
  __syncthreads();
  if (kh == 0) {
    #pragma unroll
    for (int sl = 0; sl < 3; ++sl) {
      #pragma unroll
      for (int nt = 0; nt < 2; ++nt)
        #pragma unroll
        for (int r = 0; r < 16; ++r) o[nt][r] += obuf[sl][nt][r][lane];
      lsum += lbuf[sl][c32];
    }
    if (H == 0) lfin[c32] = lsum;   // same-wave LDS round-trip (no barrier)
    float4 linv[4];
    #pragma unroll
    for (int g = 0; g < 4; ++g) {
      float4 lv = *(const float4*)&lfin[8 * g + 4 * H];
      linv[g] = make_float4(1.f / lv.x, 1.f / lv.y, 1.f / lv.z, 1.f / lv.w);
    }
    #pragma unroll
    for (int nt = 0; nt < 2; ++nt) {
      int c = hh * 64 + nt * 32 + c32;
      size_t cbase = (size_t)(c >> 3) * NTOK * 8 + (c & 7);
      #pragma unroll
      for (int r = 0; r < 16; ++r) {
        float inv = (r & 3) == 0 ? linv[r >> 2].x : (r & 3) == 1 ? linv[r >> 2].y
                  : (r & 3) == 2 ? linv[r >> 2].z : linv[r >> 2].w;
        int n = q0 + (r & 3) + 8 * (r >> 2) + 4 * H;
        afrag[cbase + (size_t)(bg * NT + n) * 8] = (short)f2bf(o[nt][r] * inv);
      }
    }
  }
}

// ================= K5: out projection, channel-split (72 x 4) ==============
__global__ __launch_bounds__(256) void oproj4(
    const short* __restrict__ afrag, const short* __restrict__ wof,
    const float* __restrict__ bo, void* __restrict__ outp,
    const int* __restrict__ flagp) {
  const int fp32 = *flagp;
  const int t = threadIdx.x, lane = t & 63, w = t >> 6;
  const int c32 = lane & 31, H = lane >> 5;
  const int t0 = blockIdx.x * 64, cg = blockIdx.y;
  const int b = (t0 >= NT) ? 1 : 0;
  const int nb0 = t0 - b * NT;
  const int tt = w & 1, chh = w >> 1;
  const int ch0 = cg * 64 + chh * 32;

  f32x16 acc;
  #pragma unroll
  for (int r = 0; r < 16; ++r) acc[r] = 0.f;
  #pragma unroll
  for (int s = 0; s < 16; ++s) {
    short8 a = *(const short8*)&wof[((size_t)(2 * s + H) * 256 + ch0 + c32) * 8];
    short8 bb = *(const short8*)&afrag[((size_t)(2 * s + H) * NTOK + t0 + tt * 32 + c32) * 8];
    acc = __builtin_amdgcn_mfma_f32_32x32x16_bf16(a, bb, acc, 0, 0, 0);
  }
  #pragma unroll
  for (int r = 0; r < 16; ++r) {
    int co = ch0 + (r & 3) + 8 * (r >> 2) + 4 * H;
    float v = acc[r] + bo[co];
    size_t off = ((size_t)(b * CC + co)) * NT + nb0 + tt * 32 + c32;
    if (fp32) ((float*)outp)[off] = v;
    else      ((u16*)outp)[off] = f2bf(v);
  }
}

extern "C" void kernel_launch(void* const* d_in, const int* in_sizes, int n_in,
                              void* d_out, int out_size, void* d_ws, size_t ws_size,
                              hipStream_t stream) {
  float* ws = (float*)d_ws;
  short* ws16 = (short*)d_ws;
  int* flag = (int*)d_ws;

  float* cb2 = ws + OFF_CB2;
  float* cbq = ws + OFF_CBQ; float* cbk = ws + OFF_CBK; float* cbv = ws + OFF_CBV;
  float* cbo = ws + OFF_CBO; float* cla = ws + OFF_CLA; float* cbeta = ws + OFF_CBETA;
  float* phif = ws + OFF_PHIF; float* phisq = ws + OFF_PHISQ;
  short* wqf = ws16 + OFF_WQF * 2;
  short* wkf = ws16 + OFF_WKF * 2;
  short* wvf = ws16 + OFF_WVF * 2;
  short* wof = ws16 + OFF_WOF * 2;
  short* w2f = ws16 + OFF_W2F * 2;
  short* xfb = ws16 + OFF_XFB * 2;
  short* qaug = ws16 + OFF_QAUG * 2;
  short* kaug = ws16 + OFF_KAUG * 2;
  short* v3   = ws16 + OFF_V3 * 2;
  short* afrag = ws16 + OFF_AFRAG * 2;

  setup_kernel<<<1158, 256, 0, stream>>>(
      d_in[0], d_in[3], d_in[5], d_in[7], d_in[9], d_in[13],
      d_in[14], d_in[4], d_in[6], d_in[8], d_in[10], d_in[15], d_in[16],
      ws, ws16, flag);
  prep_xf<<<dim3(72, 4), 256, 0, stream>>>(
      d_in[0], d_in[1], d_in[11], d_in[12], flag, w2f, cb2, phif, phisq, xfb);
  qkv_aug<<<dim3(72, 4, 4), 256, 0, stream>>>(xfb, wqf, wkf, wvf, cbq, cbk, cbv,
                                              phif, phisq, cla, cbeta,
                                              qaug, kaug, v3);
  attn_v8<<<576, 256, 0, stream>>>(qaug, kaug, v3, afrag);
  oproj4<<<dim3(72, 4), 256, 0, stream>>>(afrag, wof, cbo, d_out, flag);
}